// Round 3
// baseline (1962.780 us; speedup 1.0000x reference)
//
#include <hip/hip_runtime.h>
#include <hip/hip_bf16.h>
#include <cmath>

// Problem constants (Qwen2 MoE block)
#define TT   1024   // tokens
#define HH   2048   // hidden
#define EE   16     // experts
#define KTOP 4      // top-k
#define IM   1408   // moe intermediate
#define ISHD 5632   // shared intermediate

typedef __bf16 bf16x8 __attribute__((ext_vector_type(8)));
typedef float  f32x4  __attribute__((ext_vector_type(4)));

// load 8 consecutive fp32 (32B, 16B-aligned) and round to bf16x8 (RNE)
__device__ inline bf16x8 cvt8(const float* __restrict__ p) {
    float4 f0 = *(const float4*)p;
    float4 f1 = *(const float4*)(p + 4);
    bf16x8 r;
    r[0] = (__bf16)f0.x; r[1] = (__bf16)f0.y; r[2] = (__bf16)f0.z; r[3] = (__bf16)f0.w;
    r[4] = (__bf16)f1.x; r[5] = (__bf16)f1.y; r[6] = (__bf16)f1.z; r[7] = (__bf16)f1.w;
    return r;
}

// ---------------------------------------------------------------------------
// Kernel 1: router (fp32 exact). One block per token (256 thr = 4 waves).
// 16 logits, softmax, top-4 (fp32, unrounded weights), per-expert slot via
// atomics, shared-expert sigmoid gate, fp32 logits out.
// ---------------------------------------------------------------------------
__global__ __launch_bounds__(256) void router_kernel(
    const float* __restrict__ x,       // [TT,HH]
    const float* __restrict__ wr,      // [EE,HH]
    const float* __restrict__ wshg,    // [1,HH]
    float*  __restrict__ out_logits,   // [TT,EE]
    int*    __restrict__ counts,       // [EE] (pre-zeroed)
    int*    __restrict__ topk_e,       // [TT*KTOP]
    int*    __restrict__ topk_slot,    // [TT*KTOP]
    float*  __restrict__ topk_w,       // [TT*KTOP]
    float*  __restrict__ sgate)        // [TT]
{
    const int t    = blockIdx.x;
    const int tid  = threadIdx.x;
    const int wave = tid >> 6;
    const int lane = tid & 63;

    __shared__ float logits[EE];
    __shared__ float sgv;

    const float* xrow = x + (size_t)t * HH;
    float4 xv[4][2];
#pragma unroll
    for (int c = 0; c < 4; c++) {
        xv[c][0] = *(const float4*)(xrow + c * 512 + lane * 8);
        xv[c][1] = *(const float4*)(xrow + c * 512 + lane * 8 + 4);
    }

#pragma unroll
    for (int j = 0; j < 4; j++) {
        const int e = wave * 4 + j;
        const float* wrow = wr + (size_t)e * HH;
        float s = 0.f;
#pragma unroll
        for (int c = 0; c < 4; c++) {
            float4 w0 = *(const float4*)(wrow + c * 512 + lane * 8);
            float4 w1 = *(const float4*)(wrow + c * 512 + lane * 8 + 4);
            s += xv[c][0].x * w0.x + xv[c][0].y * w0.y + xv[c][0].z * w0.z + xv[c][0].w * w0.w;
            s += xv[c][1].x * w1.x + xv[c][1].y * w1.y + xv[c][1].z * w1.z + xv[c][1].w * w1.w;
        }
        for (int off = 32; off > 0; off >>= 1) s += __shfl_down(s, off, 64);
        if (lane == 0) logits[e] = s;
    }
    if (wave == 0) {
        float s = 0.f;
#pragma unroll
        for (int c = 0; c < 4; c++) {
            float4 w0 = *(const float4*)(wshg + c * 512 + lane * 8);
            float4 w1 = *(const float4*)(wshg + c * 512 + lane * 8 + 4);
            s += xv[c][0].x * w0.x + xv[c][0].y * w0.y + xv[c][0].z * w0.z + xv[c][0].w * w0.w;
            s += xv[c][1].x * w1.x + xv[c][1].y * w1.y + xv[c][1].z * w1.z + xv[c][1].w * w1.w;
        }
        for (int off = 32; off > 0; off >>= 1) s += __shfl_down(s, off, 64);
        if (lane == 0) sgv = s;
    }
    __syncthreads();

    if (tid == 0) {
        float mx = -1e30f;
        for (int e = 0; e < EE; e++) {
            out_logits[t * EE + e] = logits[e];
            mx = fmaxf(mx, logits[e]);
        }
        float p[EE];
        float den = 0.f;
        for (int e = 0; e < EE; e++) { p[e] = expf(logits[e] - mx); den += p[e]; }
        const float inv = 1.f / den;
        bool used[EE];
        for (int e = 0; e < EE; e++) used[e] = false;
        for (int k = 0; k < KTOP; k++) {
            int best = 0; float bv = -1.f;
            for (int e = 0; e < EE; e++)
                if (!used[e] && p[e] > bv) { bv = p[e]; best = e; }
            used[best] = true;
            float w = bv * inv;           // fp32, unrounded (matches fp32 ref)
            int slot = atomicAdd(&counts[best], 1);
            topk_e[t * KTOP + k]    = best;
            topk_slot[t * KTOP + k] = slot;
            topk_w[t * KTOP + k]    = w;
        }
        sgate[t] = 1.f / (1.f + expf(-sgv));
    }
}

// Kernel 1b: exclusive prefix sum of counts -> offsets[EE+1] (tiny)
__global__ void scan_kernel(const int* __restrict__ counts,
                            int* __restrict__ offsets) {
    if (threadIdx.x == 0 && blockIdx.x == 0) {
        int a = 0;
        for (int e = 0; e < EE; e++) { offsets[e] = a; a += counts[e]; }
        offsets[EE] = a;   // == TT*KTOP
    }
}

// Kernel 1c: scatter per-token picks into compact per-expert lists
__global__ __launch_bounds__(256) void scatter_kernel(
    const int*   __restrict__ offsets,
    const int*   __restrict__ topk_e,
    const int*   __restrict__ topk_slot,
    const float* __restrict__ topk_w,
    int*   __restrict__ tok_list,   // [TT*KTOP] compact
    float* __restrict__ wlist)      // [TT*KTOP] compact
{
    const int i = blockIdx.x * 256 + threadIdx.x;
    if (i < TT * KTOP) {
        const int e   = topk_e[i];
        const int pos = offsets[e] + topk_slot[i];
        tok_list[pos] = i >> 2;     // token index
        wlist[pos]    = topk_w[i];
    }
}

// ---------------------------------------------------------------------------
// GEMM tiling: block = 256 thr = 4 waves (2x2). Block tile 64(M) x 128(N).
// Wave tile 32x64 = 2(M) x 4(N) mfma_f32_16x16x32_bf16 tiles.
// A-frag: lane holds A[m0 + (lane&15)][k0 + (lane>>4)*8 + j]  (8 contiguous)
// B-frag: lane holds B[n0 + (lane&15)][k0 + (lane>>4)*8 + j]  of row-major W
//         (operand B = W^T).  C/D: row = (lane>>4)*4 + reg, col = lane&15.
// fp32 global data is converted to bf16 at fragment load; fp32 accumulate.
// ---------------------------------------------------------------------------

// Kernel 2/4: gate+up projection (+SiLU, +routing weight) for one expert
// (or the shared expert when counts==nullptr). Output bf16.
__global__ __launch_bounds__(256) void gateup_kernel(
    const float* __restrict__ x,         // [TT,HH] fp32
    const float* __restrict__ wgate,     // [e][I][HH] fp32
    const float* __restrict__ wup,
    const int*   __restrict__ counts,    // nullptr => shared expert (Ne=TT)
    const int*   __restrict__ offsets,   // compact row base per expert
    const int*   __restrict__ tok_list,  // compact token list
    const float* __restrict__ wlist,     // compact weights
    __bf16* __restrict__ Gout,           // compact [4096][I] (or [TT][I]) bf16
    const int I)
{
    const int e    = blockIdx.z;
    const int Ne   = counts ? counts[e]  : TT;
    const int base = counts ? offsets[e] : 0;
    const int m0 = blockIdx.y * 64;
    if (m0 >= Ne) return;
    const int n0 = blockIdx.x * 128;

    const int tid  = threadIdx.x;
    const int wave = tid >> 6, lane = tid & 63;
    const int wm = wave >> 1, wn = wave & 1;
    const int q = lane >> 4, r = lane & 15;
    const int mb = m0 + wm * 32;
    const int nb = n0 + wn * 64;

    const float* ap[2];
#pragma unroll
    for (int tm = 0; tm < 2; tm++) {
        int sc  = min(mb + tm * 16 + r, Ne - 1);
        int tok = tok_list ? tok_list[base + sc] : sc;
        ap[tm] = x + (size_t)tok * HH;
    }
    const float* bgp[4];
    const float* bup[4];
#pragma unroll
    for (int tn = 0; tn < 4; tn++) {
        int n = nb + tn * 16 + r;
        bgp[tn] = wgate + ((size_t)e * I + n) * HH;
        bup[tn] = wup   + ((size_t)e * I + n) * HH;
    }

    f32x4 accg[2][4], accu[2][4];
#pragma unroll
    for (int tm = 0; tm < 2; tm++)
#pragma unroll
        for (int tn = 0; tn < 4; tn++) {
            accg[tm][tn] = (f32x4){0.f, 0.f, 0.f, 0.f};
            accu[tm][tn] = (f32x4){0.f, 0.f, 0.f, 0.f};
        }

    for (int kk = 0; kk < HH; kk += 32) {
        const int ko = kk + q * 8;
        bf16x8 a0 = cvt8(ap[0] + ko);
        bf16x8 a1 = cvt8(ap[1] + ko);
#pragma unroll
        for (int tn = 0; tn < 4; tn++) {
            bf16x8 bg = cvt8(bgp[tn] + ko);
            bf16x8 bu = cvt8(bup[tn] + ko);
            accg[0][tn] = __builtin_amdgcn_mfma_f32_16x16x32_bf16(a0, bg, accg[0][tn], 0, 0, 0);
            accg[1][tn] = __builtin_amdgcn_mfma_f32_16x16x32_bf16(a1, bg, accg[1][tn], 0, 0, 0);
            accu[0][tn] = __builtin_amdgcn_mfma_f32_16x16x32_bf16(a0, bu, accu[0][tn], 0, 0, 0);
            accu[1][tn] = __builtin_amdgcn_mfma_f32_16x16x32_bf16(a1, bu, accu[1][tn], 0, 0, 0);
        }
    }

#pragma unroll
    for (int tm = 0; tm < 2; tm++) {
#pragma unroll
        for (int reg = 0; reg < 4; reg++) {
            const int srow = mb + tm * 16 + q * 4 + reg;
            if (srow < Ne) {
                const float w = wlist ? wlist[base + srow] : 1.f;
                __bf16* grow = Gout + (size_t)(base + srow) * I;
#pragma unroll
                for (int tn = 0; tn < 4; tn++) {
                    float g = accg[tm][tn][reg];
                    float u = accu[tm][tn][reg];
                    float act = g / (1.f + expf(-g));
                    grow[nb + tn * 16 + r] = (__bf16)(act * u * w);
                }
            }
        }
    }
}

// Kernel 3: expert down projection, atomic accumulate into fp32 moeacc[TT][HH]
__global__ __launch_bounds__(256) void down_kernel(
    const __bf16* __restrict__ G,        // compact [4096][IM] bf16
    const float*  __restrict__ wd,       // [EE][HH][IM] fp32
    const int*    __restrict__ counts,
    const int*    __restrict__ offsets,
    const int*    __restrict__ tok_list,
    float* __restrict__ moeacc)          // [TT][HH] fp32 (pre-zeroed)
{
    const int e    = blockIdx.z;
    const int Ne   = counts[e];
    const int base = offsets[e];
    const int m0 = blockIdx.y * 64;
    if (m0 >= Ne) return;
    const int n0 = blockIdx.x * 128;

    const int tid  = threadIdx.x;
    const int wave = tid >> 6, lane = tid & 63;
    const int wm = wave >> 1, wn = wave & 1;
    const int q = lane >> 4, r = lane & 15;
    const int mb = m0 + wm * 32;
    const int nb = n0 + wn * 64;

    const __bf16* ap[2];
#pragma unroll
    for (int tm = 0; tm < 2; tm++) {
        int sc = min(mb + tm * 16 + r, Ne - 1);
        ap[tm] = G + (size_t)(base + sc) * IM;
    }
    const float* bp[4];
#pragma unroll
    for (int tn = 0; tn < 4; tn++)
        bp[tn] = wd + ((size_t)e * HH + (nb + tn * 16 + r)) * IM;

    f32x4 acc[2][4];
#pragma unroll
    for (int tm = 0; tm < 2; tm++)
#pragma unroll
        for (int tn = 0; tn < 4; tn++) acc[tm][tn] = (f32x4){0.f, 0.f, 0.f, 0.f};

    for (int kk = 0; kk < IM; kk += 32) {
        const int ko = kk + q * 8;
        bf16x8 a0 = *(const bf16x8*)(ap[0] + ko);
        bf16x8 a1 = *(const bf16x8*)(ap[1] + ko);
#pragma unroll
        for (int tn = 0; tn < 4; tn++) {
            bf16x8 b = cvt8(bp[tn] + ko);
            acc[0][tn] = __builtin_amdgcn_mfma_f32_16x16x32_bf16(a0, b, acc[0][tn], 0, 0, 0);
            acc[1][tn] = __builtin_amdgcn_mfma_f32_16x16x32_bf16(a1, b, acc[1][tn], 0, 0, 0);
        }
    }

#pragma unroll
    for (int tm = 0; tm < 2; tm++) {
#pragma unroll
        for (int reg = 0; reg < 4; reg++) {
            const int srow = mb + tm * 16 + q * 4 + reg;
            if (srow < Ne) {
                const int tok = tok_list[base + srow];
#pragma unroll
                for (int tn = 0; tn < 4; tn++)
                    atomicAdd(&moeacc[(size_t)tok * HH + nb + tn * 16 + r],
                              acc[tm][tn][reg]);
            }
        }
    }
}

// Kernel 5: shared-expert down + sigmoid gate + final combine -> fp32 out
__global__ __launch_bounds__(256) void shdown_kernel(
    const __bf16* __restrict__ S,        // [TT][ISHD] bf16
    const float*  __restrict__ wsd,      // [HH][ISHD] fp32
    const float*  __restrict__ moeacc,   // [TT][HH] fp32
    const float*  __restrict__ sgate,    // [TT]
    float* __restrict__ out)             // [TT][HH] fp32
{
    const int m0 = blockIdx.y * 64;
    const int n0 = blockIdx.x * 128;

    const int tid  = threadIdx.x;
    const int wave = tid >> 6, lane = tid & 63;
    const int wm = wave >> 1, wn = wave & 1;
    const int q = lane >> 4, r = lane & 15;
    const int mb = m0 + wm * 32;
    const int nb = n0 + wn * 64;

    const __bf16* ap[2];
#pragma unroll
    for (int tm = 0; tm < 2; tm++)
        ap[tm] = S + (size_t)(mb + tm * 16 + r) * ISHD;
    const float* bp[4];
#pragma unroll
    for (int tn = 0; tn < 4; tn++)
        bp[tn] = wsd + (size_t)(nb + tn * 16 + r) * ISHD;

    f32x4 acc[2][4];
#pragma unroll
    for (int tm = 0; tm < 2; tm++)
#pragma unroll
        for (int tn = 0; tn < 4; tn++) acc[tm][tn] = (f32x4){0.f, 0.f, 0.f, 0.f};

    for (int kk = 0; kk < ISHD; kk += 32) {
        const int ko = kk + q * 8;
        bf16x8 a0 = *(const bf16x8*)(ap[0] + ko);
        bf16x8 a1 = *(const bf16x8*)(ap[1] + ko);
#pragma unroll
        for (int tn = 0; tn < 4; tn++) {
            bf16x8 b = cvt8(bp[tn] + ko);
            acc[0][tn] = __builtin_amdgcn_mfma_f32_16x16x32_bf16(a0, b, acc[0][tn], 0, 0, 0);
            acc[1][tn] = __builtin_amdgcn_mfma_f32_16x16x32_bf16(a1, b, acc[1][tn], 0, 0, 0);
        }
    }

#pragma unroll
    for (int tm = 0; tm < 2; tm++) {
#pragma unroll
        for (int reg = 0; reg < 4; reg++) {
            const int t = mb + tm * 16 + q * 4 + reg;
            const float sg = sgate[t];
#pragma unroll
            for (int tn = 0; tn < 4; tn++) {
                const int col = nb + tn * 16 + r;
                out[(size_t)t * HH + col] =
                    moeacc[(size_t)t * HH + col] + sg * acc[tm][tn][reg];
            }
        }
    }
}

// ---------------------------------------------------------------------------
extern "C" void kernel_launch(void* const* d_in, const int* in_sizes, int n_in,
                              void* d_out, int out_size, void* d_ws, size_t ws_size,
                              hipStream_t stream) {
    const float* x    = (const float*)d_in[0]; // [1,1024,2048]
    const float* wr   = (const float*)d_in[1]; // [16,2048]
    const float* wg   = (const float*)d_in[2]; // [16,1408,2048]
    const float* wu   = (const float*)d_in[3]; // [16,1408,2048]
    const float* wd   = (const float*)d_in[4]; // [16,2048,1408]
    const float* wsg  = (const float*)d_in[5]; // [5632,2048]
    const float* wsu  = (const float*)d_in[6]; // [5632,2048]
    const float* wsd  = (const float*)d_in[7]; // [2048,5632]
    const float* wshg = (const float*)d_in[8]; // [1,2048]

    float* out        = (float*)d_out;            // final [1024,2048] fp32
    float* out_logits = out + (size_t)TT * HH;    // router_logits [1024,16] fp32

    // workspace layout (~19.1 MiB; G and S alias: G dies before S is born)
    char* ws = (char*)d_ws;
    int*    counts    = (int*)(ws + 0);                 // 64 B (pad 256)
    int*    offsets   = (int*)(ws + 256);               // 68 B (pad 256)
    int*    topk_e    = (int*)(ws + 512);               // 16 KB
    int*    topk_slot = (int*)(ws + 512 + 16384);       // 16 KB
    float*  topk_w    = (float*)(ws + 512 + 32768);     // 16 KB
    float*  sgate     = (float*)(ws + 512 + 49152);     // 4 KB
    int*    tok_list  = (int*)(ws + 512 + 53248);       // 16 KB
    float*  wlist     = (float*)(ws + 512 + 69632);     // 16 KB
    float*  moeacc    = (float*)(ws + 512 + 86016);     // 8 MB  [TT][HH] f32
    char*   GS        = (char*)moeacc + (size_t)TT * HH * 4;  // 11.5 MB
    __bf16* G = (__bf16*)GS;   // compact [TT*KTOP][IM] bf16   (phase 1)
    __bf16* S = (__bf16*)GS;   // [TT][ISHD] bf16               (phase 2, aliases G)

    hipMemsetAsync(counts, 0, EE * sizeof(int), stream);
    hipMemsetAsync(moeacc, 0, (size_t)TT * HH * sizeof(float), stream);

    router_kernel<<<TT, 256, 0, stream>>>(x, wr, wshg, out_logits,
                                          counts, topk_e, topk_slot, topk_w, sgate);
    scan_kernel<<<1, 64, 0, stream>>>(counts, offsets);
    scatter_kernel<<<(TT * KTOP + 255) / 256, 256, 0, stream>>>(
        offsets, topk_e, topk_slot, topk_w, tok_list, wlist);

    // experts: gate/up (+silu * up * routing weight) -> compact G (bf16)
    gateup_kernel<<<dim3(IM / 128, TT / 64, EE), 256, 0, stream>>>(
        x, wg, wu, counts, offsets, tok_list, wlist, G, IM);

    // experts: down -> atomic accumulate into moeacc (fp32)
    down_kernel<<<dim3(HH / 128, TT / 64, EE), 256, 0, stream>>>(
        G, wd, counts, offsets, tok_list, moeacc);

    // shared expert gate/up -> S (aliases G region; G is dead now)
    gateup_kernel<<<dim3(ISHD / 128, TT / 64, 1), 256, 0, stream>>>(
        x, wsg, wsu, nullptr, nullptr, nullptr, nullptr, S, ISHD);

    // shared down + sigmoid gate + combine -> fp32 out
    shdown_kernel<<<dim3(HH / 128, TT / 64, 1), 256, 0, stream>>>(
        S, wsd, moeacc, sgate, out);
}

// Round 4
// 890.102 us; speedup vs baseline: 2.2051x; 2.2051x over previous
//
#include <hip/hip_runtime.h>
#include <hip/hip_bf16.h>
#include <cmath>

// Problem constants (Qwen2 MoE block)
#define TT   1024   // tokens
#define HH   2048   // hidden
#define EE   16     // experts
#define KTOP 4      // top-k
#define IM   1408   // moe intermediate
#define ISHD 5632   // shared intermediate
#define BK   64     // K-slice staged in LDS

typedef __bf16 bf16x8 __attribute__((ext_vector_type(8)));
typedef __bf16 bf16x4 __attribute__((ext_vector_type(4)));
typedef float  f32x4  __attribute__((ext_vector_type(4)));

__device__ inline bf16x4 cvt4(float4 f) {
    bf16x4 r;
    r[0] = (__bf16)f.x; r[1] = (__bf16)f.y; r[2] = (__bf16)f.z; r[3] = (__bf16)f.w;
    return r;
}

// ---------------------------------------------------------------------------
// Kernel 0: convert x fp32 -> bf16 once (A-side of all gate/up GEMMs)
// ---------------------------------------------------------------------------
__global__ __launch_bounds__(256) void cvtx_kernel(
    const float* __restrict__ x, __bf16* __restrict__ xb) {
    const int i = (blockIdx.x * 256 + threadIdx.x) * 4;
    *(bf16x4*)(xb + i) = cvt4(*(const float4*)(x + i));
}

// ---------------------------------------------------------------------------
// Kernel 1: router (fp32 exact). One block per token.
// ---------------------------------------------------------------------------
__global__ __launch_bounds__(256) void router_kernel(
    const float* __restrict__ x, const float* __restrict__ wr,
    const float* __restrict__ wshg,
    float* __restrict__ out_logits, int* __restrict__ counts,
    int* __restrict__ topk_e, int* __restrict__ topk_slot,
    float* __restrict__ topk_w, float* __restrict__ sgate)
{
    const int t    = blockIdx.x;
    const int tid  = threadIdx.x;
    const int wave = tid >> 6;
    const int lane = tid & 63;

    __shared__ float logits[EE];
    __shared__ float sgv;

    const float* xrow = x + (size_t)t * HH;
    float4 xv[4][2];
#pragma unroll
    for (int c = 0; c < 4; c++) {
        xv[c][0] = *(const float4*)(xrow + c * 512 + lane * 8);
        xv[c][1] = *(const float4*)(xrow + c * 512 + lane * 8 + 4);
    }

#pragma unroll
    for (int j = 0; j < 4; j++) {
        const int e = wave * 4 + j;
        const float* wrow = wr + (size_t)e * HH;
        float s = 0.f;
#pragma unroll
        for (int c = 0; c < 4; c++) {
            float4 w0 = *(const float4*)(wrow + c * 512 + lane * 8);
            float4 w1 = *(const float4*)(wrow + c * 512 + lane * 8 + 4);
            s += xv[c][0].x * w0.x + xv[c][0].y * w0.y + xv[c][0].z * w0.z + xv[c][0].w * w0.w;
            s += xv[c][1].x * w1.x + xv[c][1].y * w1.y + xv[c][1].z * w1.z + xv[c][1].w * w1.w;
        }
        for (int off = 32; off > 0; off >>= 1) s += __shfl_down(s, off, 64);
        if (lane == 0) logits[e] = s;
    }
    if (wave == 0) {
        float s = 0.f;
#pragma unroll
        for (int c = 0; c < 4; c++) {
            float4 w0 = *(const float4*)(wshg + c * 512 + lane * 8);
            float4 w1 = *(const float4*)(wshg + c * 512 + lane * 8 + 4);
            s += xv[c][0].x * w0.x + xv[c][0].y * w0.y + xv[c][0].z * w0.z + xv[c][0].w * w0.w;
            s += xv[c][1].x * w1.x + xv[c][1].y * w1.y + xv[c][1].z * w1.z + xv[c][1].w * w1.w;
        }
        for (int off = 32; off > 0; off >>= 1) s += __shfl_down(s, off, 64);
        if (lane == 0) sgv = s;
    }
    __syncthreads();

    if (tid == 0) {
        float mx = -1e30f;
        for (int e = 0; e < EE; e++) {
            out_logits[t * EE + e] = logits[e];
            mx = fmaxf(mx, logits[e]);
        }
        float p[EE]; float den = 0.f;
        for (int e = 0; e < EE; e++) { p[e] = expf(logits[e] - mx); den += p[e]; }
        const float inv = 1.f / den;
        bool used[EE];
        for (int e = 0; e < EE; e++) used[e] = false;
        for (int k = 0; k < KTOP; k++) {
            int best = 0; float bv = -1.f;
            for (int e = 0; e < EE; e++)
                if (!used[e] && p[e] > bv) { bv = p[e]; best = e; }
            used[best] = true;
            int slot = atomicAdd(&counts[best], 1);
            topk_e[t * KTOP + k]    = best;
            topk_slot[t * KTOP + k] = slot;
            topk_w[t * KTOP + k]    = bv * inv;   // fp32 unrounded
        }
        sgate[t] = 1.f / (1.f + expf(-sgv));
    }
}

__global__ void scan_kernel(const int* __restrict__ counts,
                            int* __restrict__ offsets) {
    if (threadIdx.x == 0 && blockIdx.x == 0) {
        int a = 0;
        for (int e = 0; e < EE; e++) { offsets[e] = a; a += counts[e]; }
        offsets[EE] = a;
    }
}

__global__ __launch_bounds__(256) void scatter_kernel(
    const int* __restrict__ offsets, const int* __restrict__ topk_e,
    const int* __restrict__ topk_slot, const float* __restrict__ topk_w,
    int* __restrict__ tok_list, float* __restrict__ wlist)
{
    const int i = blockIdx.x * 256 + threadIdx.x;
    if (i < TT * KTOP) {
        const int e   = topk_e[i];
        const int pos = offsets[e] + topk_slot[i];
        tok_list[pos] = i >> 2;
        wlist[pos]    = topk_w[i];
    }
}

// ---------------------------------------------------------------------------
// Kernel 2/4: gate+up dual GEMM. BM=128, BN=64, BK=64, LDS-staged,
// register-prefetch of next K-slice. A from xb (bf16, token-gathered);
// B = wgate/wup rows (fp32 -> bf16 at staging). Epilogue silu(g)*u*w -> bf16.
// LDS rows padded +8 bf16 -> conflict-free b128/b64 patterns (uniform 8/bank).
// ---------------------------------------------------------------------------
__global__ __launch_bounds__(256) void gateup_kernel(
    const __bf16* __restrict__ xb, const float* __restrict__ wgate,
    const float* __restrict__ wup, const int* __restrict__ counts,
    const int* __restrict__ offsets, const int* __restrict__ tok_list,
    const float* __restrict__ wlist, __bf16* __restrict__ Gout, const int I)
{
    const int e    = blockIdx.z;
    const int Ne   = counts ? counts[e]  : TT;
    const int base = counts ? offsets[e] : 0;
    const int m0 = blockIdx.y * 128;
    if (m0 >= Ne) return;
    const int n0 = blockIdx.x * 64;

    __shared__ __bf16 As[128][72];
    __shared__ __bf16 Bgs[64][72];
    __shared__ __bf16 Bus[64][72];

    const int tid = threadIdx.x;
    // A staging: 32 rows/pass x (8 thr x 8 el), 4 passes
    const int arow = tid >> 3;
    const int acg  = tid & 7;
    const __bf16* aptr[4];
#pragma unroll
    for (int p = 0; p < 4; p++) {
        int sc  = min(m0 + p * 32 + arow, Ne - 1);
        int tok = tok_list ? tok_list[base + sc] : sc;
        aptr[p] = xb + (size_t)tok * HH + acg * 8;
    }
    // B staging: 16 rows/pass x (16 thr x float4), 4 passes
    const int brow = tid >> 4;
    const int bc4  = tid & 15;
    const float* bgptr[4];
    const float* buptr[4];
#pragma unroll
    for (int p = 0; p < 4; p++) {
        size_t off = ((size_t)e * I + n0 + p * 16 + brow) * HH + bc4 * 4;
        bgptr[p] = wgate + off;
        buptr[p] = wup   + off;
    }

    const int wave = tid >> 6, lane = tid & 63;
    const int wm = wave >> 1, wn = wave & 1;
    const int q = lane >> 4, r = lane & 15;

    f32x4 accg[4][2], accu[4][2];
#pragma unroll
    for (int i = 0; i < 4; i++)
#pragma unroll
        for (int j = 0; j < 2; j++) {
            accg[i][j] = (f32x4){0.f, 0.f, 0.f, 0.f};
            accu[i][j] = (f32x4){0.f, 0.f, 0.f, 0.f};
        }

    bf16x8 av[4]; float4 bgv[4], buv[4];
#pragma unroll
    for (int p = 0; p < 4; p++) {
        av[p]  = *(const bf16x8*)(aptr[p]);
        bgv[p] = *(const float4*)(bgptr[p]);
        buv[p] = *(const float4*)(buptr[p]);
    }

    for (int kk = 0; kk < HH; kk += BK) {
        __syncthreads();
#pragma unroll
        for (int p = 0; p < 4; p++) {
            *(bf16x8*)&As[p * 32 + arow][acg * 8]  = av[p];
            *(bf16x4*)&Bgs[p * 16 + brow][bc4 * 4] = cvt4(bgv[p]);
            *(bf16x4*)&Bus[p * 16 + brow][bc4 * 4] = cvt4(buv[p]);
        }
        __syncthreads();
        if (kk + BK < HH) {
            const int ko = kk + BK;
#pragma unroll
            for (int p = 0; p < 4; p++) {
                av[p]  = *(const bf16x8*)(aptr[p] + ko);
                bgv[p] = *(const float4*)(bgptr[p] + ko);
                buv[p] = *(const float4*)(buptr[p] + ko);
            }
        }
#pragma unroll
        for (int ks = 0; ks < BK; ks += 32) {
            bf16x8 af[4], bgf[2], buf[2];
#pragma unroll
            for (int i = 0; i < 4; i++)
                af[i] = *(const bf16x8*)&As[wm * 64 + i * 16 + r][ks + q * 8];
#pragma unroll
            for (int j = 0; j < 2; j++) {
                bgf[j] = *(const bf16x8*)&Bgs[wn * 32 + j * 16 + r][ks + q * 8];
                buf[j] = *(const bf16x8*)&Bus[wn * 32 + j * 16 + r][ks + q * 8];
            }
#pragma unroll
            for (int i = 0; i < 4; i++)
#pragma unroll
                for (int j = 0; j < 2; j++) {
                    accg[i][j] = __builtin_amdgcn_mfma_f32_16x16x32_bf16(af[i], bgf[j], accg[i][j], 0, 0, 0);
                    accu[i][j] = __builtin_amdgcn_mfma_f32_16x16x32_bf16(af[i], buf[j], accu[i][j], 0, 0, 0);
                }
        }
    }

#pragma unroll
    for (int i = 0; i < 4; i++)
#pragma unroll
        for (int reg = 0; reg < 4; reg++) {
            const int srow = m0 + wm * 64 + i * 16 + q * 4 + reg;
            if (srow < Ne) {
                const float w = wlist ? wlist[base + srow] : 1.f;
                __bf16* gp = Gout + (size_t)(base + srow) * I + n0 + wn * 32;
#pragma unroll
                for (int j = 0; j < 2; j++) {
                    float g = accg[i][j][reg];
                    float u = accu[i][j][reg];
                    float act = g / (1.f + expf(-g));
                    gp[j * 16 + r] = (__bf16)(act * u * w);
                }
            }
        }
}

// ---------------------------------------------------------------------------
// Kernel 3: expert down GEMM. BM=128, BN=128, BK=64, LDS-staged.
// A = compact G (bf16); B = wd rows (fp32->bf16). Epilogue: atomicAdd fp32.
// ---------------------------------------------------------------------------
__global__ __launch_bounds__(256) void down_kernel(
    const __bf16* __restrict__ G, const float* __restrict__ wd,
    const int* __restrict__ counts, const int* __restrict__ offsets,
    const int* __restrict__ tok_list, float* __restrict__ moeacc)
{
    const int e    = blockIdx.z;
    const int Ne   = counts[e];
    const int base = offsets[e];
    const int m0 = blockIdx.y * 128;
    if (m0 >= Ne) return;
    const int n0 = blockIdx.x * 128;

    __shared__ __bf16 As[128][72];
    __shared__ __bf16 Bs[128][72];

    const int tid = threadIdx.x;
    const int arow = tid >> 3;
    const int acg  = tid & 7;
    const __bf16* aptr[4];
#pragma unroll
    for (int p = 0; p < 4; p++) {
        int sc = min(m0 + p * 32 + arow, Ne - 1);
        aptr[p] = G + (size_t)(base + sc) * IM + acg * 8;
    }
    const int brow = tid >> 4;
    const int bc4  = tid & 15;
    const float* bptr[8];
#pragma unroll
    for (int p = 0; p < 8; p++)
        bptr[p] = wd + ((size_t)e * HH + n0 + p * 16 + brow) * IM + bc4 * 4;

    const int wave = tid >> 6, lane = tid & 63;
    const int wm = wave >> 1, wn = wave & 1;
    const int q = lane >> 4, r = lane & 15;

    f32x4 acc[4][4];
#pragma unroll
    for (int i = 0; i < 4; i++)
#pragma unroll
        for (int j = 0; j < 4; j++) acc[i][j] = (f32x4){0.f, 0.f, 0.f, 0.f};

    bf16x8 av[4]; float4 bv[8];
#pragma unroll
    for (int p = 0; p < 4; p++) av[p] = *(const bf16x8*)(aptr[p]);
#pragma unroll
    for (int p = 0; p < 8; p++) bv[p] = *(const float4*)(bptr[p]);

    for (int kk = 0; kk < IM; kk += BK) {
        __syncthreads();
#pragma unroll
        for (int p = 0; p < 4; p++)
            *(bf16x8*)&As[p * 32 + arow][acg * 8] = av[p];
#pragma unroll
        for (int p = 0; p < 8; p++)
            *(bf16x4*)&Bs[p * 16 + brow][bc4 * 4] = cvt4(bv[p]);
        __syncthreads();
        if (kk + BK < IM) {
            const int ko = kk + BK;
#pragma unroll
            for (int p = 0; p < 4; p++) av[p] = *(const bf16x8*)(aptr[p] + ko);
#pragma unroll
            for (int p = 0; p < 8; p++) bv[p] = *(const float4*)(bptr[p] + ko);
        }
#pragma unroll
        for (int ks = 0; ks < BK; ks += 32) {
            bf16x8 af[4], bf[4];
#pragma unroll
            for (int i = 0; i < 4; i++)
                af[i] = *(const bf16x8*)&As[wm * 64 + i * 16 + r][ks + q * 8];
#pragma unroll
            for (int j = 0; j < 4; j++)
                bf[j] = *(const bf16x8*)&Bs[wn * 64 + j * 16 + r][ks + q * 8];
#pragma unroll
            for (int i = 0; i < 4; i++)
#pragma unroll
                for (int j = 0; j < 4; j++)
                    acc[i][j] = __builtin_amdgcn_mfma_f32_16x16x32_bf16(af[i], bf[j], acc[i][j], 0, 0, 0);
        }
    }

#pragma unroll
    for (int i = 0; i < 4; i++)
#pragma unroll
        for (int reg = 0; reg < 4; reg++) {
            const int srow = m0 + wm * 64 + i * 16 + q * 4 + reg;
            if (srow < Ne) {
                const int tok = tok_list[base + srow];
                float* mp = moeacc + (size_t)tok * HH + n0 + wn * 64;
#pragma unroll
                for (int j = 0; j < 4; j++)
                    atomicAdd(mp + j * 16 + r, acc[i][j][reg]);
            }
        }
}

// ---------------------------------------------------------------------------
// Kernel 5: shared down + sigmoid gate + combine. BM=128, BN=64, BK=64.
// A = S (bf16), B = wsd (fp32->bf16). Epilogue: out = moeacc + sg*acc (fp32).
// ---------------------------------------------------------------------------
__global__ __launch_bounds__(256) void shdown_kernel(
    const __bf16* __restrict__ S, const float* __restrict__ wsd,
    const float* __restrict__ moeacc, const float* __restrict__ sgate,
    float* __restrict__ out)
{
    const int m0 = blockIdx.y * 128;
    const int n0 = blockIdx.x * 64;

    __shared__ __bf16 As[128][72];
    __shared__ __bf16 Bs[64][72];

    const int tid = threadIdx.x;
    const int arow = tid >> 3;
    const int acg  = tid & 7;
    const __bf16* aptr[4];
#pragma unroll
    for (int p = 0; p < 4; p++)
        aptr[p] = S + (size_t)(m0 + p * 32 + arow) * ISHD + acg * 8;
    const int brow = tid >> 4;
    const int bc4  = tid & 15;
    const float* bptr[4];
#pragma unroll
    for (int p = 0; p < 4; p++)
        bptr[p] = wsd + (size_t)(n0 + p * 16 + brow) * ISHD + bc4 * 4;

    const int wave = tid >> 6, lane = tid & 63;
    const int wm = wave >> 1, wn = wave & 1;
    const int q = lane >> 4, r = lane & 15;

    f32x4 acc[4][2];
#pragma unroll
    for (int i = 0; i < 4; i++)
#pragma unroll
        for (int j = 0; j < 2; j++) acc[i][j] = (f32x4){0.f, 0.f, 0.f, 0.f};

    bf16x8 av[4]; float4 bv[4];
#pragma unroll
    for (int p = 0; p < 4; p++) {
        av[p] = *(const bf16x8*)(aptr[p]);
        bv[p] = *(const float4*)(bptr[p]);
    }

    for (int kk = 0; kk < ISHD; kk += BK) {
        __syncthreads();
#pragma unroll
        for (int p = 0; p < 4; p++) {
            *(bf16x8*)&As[p * 32 + arow][acg * 8]  = av[p];
            *(bf16x4*)&Bs[p * 16 + brow][bc4 * 4] = cvt4(bv[p]);
        }
        __syncthreads();
        if (kk + BK < ISHD) {
            const int ko = kk + BK;
#pragma unroll
            for (int p = 0; p < 4; p++) {
                av[p] = *(const bf16x8*)(aptr[p] + ko);
                bv[p] = *(const float4*)(bptr[p] + ko);
            }
        }
#pragma unroll
        for (int ks = 0; ks < BK; ks += 32) {
            bf16x8 af[4], bf[2];
#pragma unroll
            for (int i = 0; i < 4; i++)
                af[i] = *(const bf16x8*)&As[wm * 64 + i * 16 + r][ks + q * 8];
#pragma unroll
            for (int j = 0; j < 2; j++)
                bf[j] = *(const bf16x8*)&Bs[wn * 32 + j * 16 + r][ks + q * 8];
#pragma unroll
            for (int i = 0; i < 4; i++)
#pragma unroll
                for (int j = 0; j < 2; j++)
                    acc[i][j] = __builtin_amdgcn_mfma_f32_16x16x32_bf16(af[i], bf[j], acc[i][j], 0, 0, 0);
        }
    }

#pragma unroll
    for (int i = 0; i < 4; i++)
#pragma unroll
        for (int reg = 0; reg < 4; reg++) {
            const int t  = m0 + wm * 64 + i * 16 + q * 4 + reg;
            const float sg = sgate[t];
            const float* mp = moeacc + (size_t)t * HH + n0 + wn * 32;
            float* op = out + (size_t)t * HH + n0 + wn * 32;
#pragma unroll
            for (int j = 0; j < 2; j++)
                op[j * 16 + r] = mp[j * 16 + r] + sg * acc[i][j][reg];
        }
}

// ---------------------------------------------------------------------------
extern "C" void kernel_launch(void* const* d_in, const int* in_sizes, int n_in,
                              void* d_out, int out_size, void* d_ws, size_t ws_size,
                              hipStream_t stream) {
    const float* x    = (const float*)d_in[0];
    const float* wr   = (const float*)d_in[1];
    const float* wg   = (const float*)d_in[2];
    const float* wu   = (const float*)d_in[3];
    const float* wd   = (const float*)d_in[4];
    const float* wsg  = (const float*)d_in[5];
    const float* wsu  = (const float*)d_in[6];
    const float* wsd  = (const float*)d_in[7];
    const float* wshg = (const float*)d_in[8];

    float* out        = (float*)d_out;
    float* out_logits = out + (size_t)TT * HH;

    // workspace layout (~23.1 MiB; G and S alias: G dies before S is born)
    char* ws = (char*)d_ws;
    int*    counts    = (int*)(ws + 0);
    int*    offsets   = (int*)(ws + 256);
    int*    topk_e    = (int*)(ws + 512);
    int*    topk_slot = (int*)(ws + 512 + 16384);
    float*  topk_w    = (float*)(ws + 512 + 32768);
    float*  sgate     = (float*)(ws + 512 + 49152);
    int*    tok_list  = (int*)(ws + 512 + 53248);
    float*  wlist     = (float*)(ws + 512 + 69632);
    __bf16* xb        = (__bf16*)(ws + 86528);                 // 4 MB [TT][HH] bf16
    float*  moeacc    = (float*)(ws + 86528 + 4194304);        // 8 MB [TT][HH] f32
    char*   GS        = (char*)moeacc + (size_t)TT * HH * 4;   // 11.5 MB
    __bf16* G = (__bf16*)GS;   // compact [TT*KTOP][IM] bf16
    __bf16* S = (__bf16*)GS;   // [TT][ISHD] bf16 (aliases G)

    hipMemsetAsync(counts, 0, EE * sizeof(int), stream);
    hipMemsetAsync(moeacc, 0, (size_t)TT * HH * sizeof(float), stream);

    cvtx_kernel<<<TT * HH / 1024, 256, 0, stream>>>(x, xb);
    router_kernel<<<TT, 256, 0, stream>>>(x, wr, wshg, out_logits,
                                          counts, topk_e, topk_slot, topk_w, sgate);
    scan_kernel<<<1, 64, 0, stream>>>(counts, offsets);
    scatter_kernel<<<(TT * KTOP + 255) / 256, 256, 0, stream>>>(
        offsets, topk_e, topk_slot, topk_w, tok_list, wlist);

    // experts: gate/up -> compact G (bf16)
    gateup_kernel<<<dim3(IM / 64, TT / 128, EE), 256, 0, stream>>>(
        xb, wg, wu, counts, offsets, tok_list, wlist, G, IM);

    // experts: down -> atomic accumulate into moeacc
    down_kernel<<<dim3(HH / 128, TT / 128, EE), 256, 0, stream>>>(
        G, wd, counts, offsets, tok_list, moeacc);

    // shared expert gate/up -> S
    gateup_kernel<<<dim3(ISHD / 64, TT / 128, 1), 256, 0, stream>>>(
        xb, wsg, wsu, nullptr, nullptr, nullptr, nullptr, S, ISHD);

    // shared down + sigmoid gate + combine -> fp32 out
    shdown_kernel<<<dim3(HH / 64, TT / 128, 1), 256, 0, stream>>>(
        S, wsd, moeacc, sgate, out);
}